// Round 1
// baseline (396.208 us; speedup 1.0000x reference)
//
#include <hip/hip_runtime.h>

#define NB 2048
#define S_ 200
#define C_ 25
#define H_ 8
#define CP 28  // padded row stride (floats), 112 B = 16B-aligned rows

struct Row25 { float v[25]; };

__device__ __forceinline__ Row25 ldrow(const float* __restrict__ p) {
    Row25 r;
    const float4* p4 = (const float4*)p;
#pragma unroll
    for (int i = 0; i < 6; ++i) {
        float4 q = p4[i];
        r.v[4*i+0] = q.x; r.v[4*i+1] = q.y; r.v[4*i+2] = q.z; r.v[4*i+3] = q.w;
    }
    r.v[24] = p[24];
    return r;
}

__device__ __forceinline__ float dot25(const Row25& a, const Row25& b) {
    float s0 = 0.f, s1 = 0.f, s2 = 0.f, s3 = 0.f;
#pragma unroll
    for (int i = 0; i < 24; i += 4) {
        s0 = fmaf(a.v[i+0], b.v[i+0], s0);
        s1 = fmaf(a.v[i+1], b.v[i+1], s1);
        s2 = fmaf(a.v[i+2], b.v[i+2], s2);
        s3 = fmaf(a.v[i+3], b.v[i+3], s3);
    }
    s0 = fmaf(a.v[24], b.v[24], s0);
    return (s0 + s1) + (s2 + s3);
}

__global__ __launch_bounds__(256, 2) void ssm_syn_delay_kernel(
    const float* __restrict__ x,       const float* __restrict__ delay_W,
    const float* __restrict__ delay_b, const float* __restrict__ U_W,
    const float* __restrict__ U_b,     const float* __restrict__ A_W,
    const float* __restrict__ B_W,     const float* __restrict__ B_b,
    const float* __restrict__ out_W,   const float* __restrict__ out_b,
    float* __restrict__ out)
{
    __shared__ float xs[S_ * CP];    // x[b] rows, padded
    __shared__ float dw[S_ * CP];    // delay_W rows, padded
    __shared__ float dbs[S_];
    __shared__ float rden[S_];       // 1/denom per source timestep t
    __shared__ float p_s[S_ * H_];   // bgate * u
    __shared__ float hs_s[S_ * H_];
    __shared__ float uw_s[H_ * CP];
    __shared__ float bw_s[H_ * CP];
    __shared__ float aw_s[H_ * H_];
    __shared__ float ow_s[C_ * H_];
    __shared__ float ub_s[H_], bb_s[H_], ob_s[C_];

    const int tid = threadIdx.x;
    const int b   = blockIdx.x;
    const float* xb = x + (size_t)b * (S_ * C_);

    // ---- Phase 0: stage everything into LDS (coalesced global reads) ----
    for (int i = tid; i < S_ * C_; i += 256) {
        int r = i / C_, c = i - r * C_;
        xs[r * CP + c] = xb[i];
        dw[r * CP + c] = delay_W[i];
    }
    for (int i = tid; i < S_; i += 256) dbs[i] = delay_b[i];
    for (int i = tid; i < H_ * C_; i += 256) {
        int r = i / C_, c = i - r * C_;
        uw_s[r * CP + c] = U_W[i];
        bw_s[r * CP + c] = B_W[i];
    }
    for (int i = tid; i < H_ * H_; i += 256) aw_s[i] = A_W[i];
    for (int i = tid; i < C_ * H_; i += 256) ow_s[i] = out_W[i];
    if (tid < H_) { ub_s[tid] = U_b[tid]; bb_s[tid] = B_b[tid]; }
    if (tid < C_) ob_s[tid] = out_b[tid];
    __syncthreads();

    // ---- Phase 1: softmax denominators per source row t ----
    // thread = (tg, half): owns rows t0=tg, t1=tg+128 (clamped); scans s-half.
    {
        const int half = tid & 1;
        const int tg   = tid >> 1;            // 0..127
        const int t0   = tg;
        const int t1   = tg + 128;
        const int t1c  = (t1 < S_) ? t1 : (S_ - 1);
        Row25 xr0 = ldrow(&xs[t0 * CP]);
        Row25 xr1 = ldrow(&xs[t1c * CP]);
        float d0 = 0.f, d1 = 0.f;
        const int sbase = half * 100;
        for (int si = 0; si < 100; ++si) {
            const int s = sbase + si;
            Row25 wr = ldrow(&dw[s * CP]);   // 2 distinct rows per wave
            float bias = dbs[s];
            float l0 = bias + dot25(xr0, wr);
            float l1 = bias + dot25(xr1, wr);
            d0 += __expf(l0);
            d1 += __expf(l1);
        }
        d0 += __shfl_xor(d0, 1);
        d1 += __shfl_xor(d1, 1);
        if (half == 0)       rden[t0] = 1.0f / d0;
        else if (t1 < S_)    rden[t1] = 1.0f / d1;
    }
    __syncthreads();

    // ---- Phase 2: x_del columns + u / bgate (recompute logits) ----
    // thread = (sg, th): owns out-timesteps s0=sg, s1=sg+128 (clamped); scans t-half.
    {
        const int th = tid & 1;
        const int sg = tid >> 1;              // 0..127
        const int s0 = sg;
        const int s1 = sg + 128;
        const int s1c = (s1 < S_) ? s1 : (S_ - 1);
        Row25 w0 = ldrow(&dw[s0 * CP]);
        Row25 w1 = ldrow(&dw[s1c * CP]);
        const float bias0 = dbs[s0];
        const float bias1 = dbs[s1c];
        Row25 acc0, acc1;
#pragma unroll
        for (int i = 0; i < 25; ++i) { acc0.v[i] = 0.f; acc1.v[i] = 0.f; }

        const int tbase = th * 100;
        for (int ti = 0; ti < 100; ++ti) {
            const int t = tbase + ti;
            Row25 xr = ldrow(&xs[t * CP]);   // 2 distinct rows per wave
            float l0 = bias0 + dot25(xr, w0);
            float l1 = bias1 + dot25(xr, w1);
            float rd = rden[t];
            float e0 = __expf(l0) * rd;
            float e1 = __expf(l1) * rd;
#pragma unroll
            for (int i = 0; i < 25; ++i) {
                acc0.v[i] = fmaf(e0, xr.v[i], acc0.v[i]);
                acc1.v[i] = fmaf(e1, xr.v[i], acc1.v[i]);
            }
        }
        // combine the two t-halves across the lane pair
#pragma unroll
        for (int i = 0; i < 25; ++i) {
            acc0.v[i] += __shfl_xor(acc0.v[i], 1);
            acc1.v[i] += __shfl_xor(acc1.v[i], 1);
        }
        const int smine = th ? s1 : s0;
        if (smine < S_) {
            Row25 a;
#pragma unroll
            for (int i = 0; i < 25; ++i) a.v[i] = th ? acc1.v[i] : acc0.v[i];
#pragma unroll
            for (int h = 0; h < H_; ++h) {
                Row25 uw = ldrow(&uw_s[h * CP]);
                Row25 bw = ldrow(&bw_s[h * CP]);
                float uu = ub_s[h] + dot25(a, uw);
                float bb = bb_s[h] + dot25(a, bw);
                float sg_ = 1.0f / (1.0f + __expf(-bb));
                p_s[smine * H_ + h] = uu * sg_;
            }
        }
    }
    __syncthreads();

    // ---- Phase 3: linear recurrence h_s = A h_{s-1} + p_s (8 lanes) ----
    if (tid < H_) {
        const int i = tid;
        float Ar[H_];
#pragma unroll
        for (int j = 0; j < H_; ++j) Ar[j] = aw_s[i * H_ + j];
        float h = 0.f;
        for (int s = 0; s < S_; ++s) {
            float acc = p_s[s * H_ + i];
#pragma unroll
            for (int j = 0; j < H_; ++j)
                acc = fmaf(Ar[j], __shfl(h, j, 8), acc);
            h = acc;
            hs_s[s * H_ + i] = h;
        }
    }
    __syncthreads();

    // ---- Phase 4: out[b,s,c] = hs[s]·out_W[c,:] + out_b[c] ----
    float* ob_ptr = out + (size_t)b * (S_ * C_);
    for (int i = tid; i < S_ * C_; i += 256) {
        int s = i / C_, c = i - s * C_;
        float v = ob_s[c];
#pragma unroll
        for (int h = 0; h < H_; ++h)
            v = fmaf(hs_s[s * H_ + h], ow_s[c * H_ + h], v);
        ob_ptr[i] = v;
    }
}

extern "C" void kernel_launch(void* const* d_in, const int* in_sizes, int n_in,
                              void* d_out, int out_size, void* d_ws, size_t ws_size,
                              hipStream_t stream) {
    const float* x       = (const float*)d_in[0];
    const float* delay_W = (const float*)d_in[1];
    const float* delay_b = (const float*)d_in[2];
    const float* U_W     = (const float*)d_in[3];
    const float* U_b     = (const float*)d_in[4];
    const float* A_W     = (const float*)d_in[5];
    const float* B_W     = (const float*)d_in[6];
    const float* B_b     = (const float*)d_in[7];
    const float* out_W   = (const float*)d_in[8];
    const float* out_b   = (const float*)d_in[9];
    float* out = (float*)d_out;

    ssm_syn_delay_kernel<<<NB, 256, 0, stream>>>(
        x, delay_W, delay_b, U_W, U_b, A_W, B_W, B_b, out_W, out_b, out);
}

// Round 2
// 357.104 us; speedup vs baseline: 1.1095x; 1.1095x over previous
//
#include <hip/hip_runtime.h>

#define NB 2048
#define S_ 200
#define C_ 25
#define H_ 8
#define CP 28  // padded row stride (floats), 112 B = 16B-aligned rows

struct Row25 { float v[25]; };

__device__ __forceinline__ Row25 ldrow(const float* __restrict__ p) {
    Row25 r;
    const float4* p4 = (const float4*)p;
#pragma unroll
    for (int i = 0; i < 6; ++i) {
        float4 q = p4[i];
        r.v[4*i+0] = q.x; r.v[4*i+1] = q.y; r.v[4*i+2] = q.z; r.v[4*i+3] = q.w;
    }
    r.v[24] = p[24];
    return r;
}

// Opaque pin: forces the 25 elements into live VGPRs; the compiler cannot
// rematerialize them from LDS inside later loops (asm is not duplicable).
__device__ __forceinline__ void pin(Row25& r) {
#pragma unroll
    for (int i = 0; i < 25; ++i) asm volatile("" : "+v"(r.v[i]));
}

__device__ __forceinline__ float dot25(const Row25& a, const Row25& b) {
    float s0 = 0.f, s1 = 0.f, s2 = 0.f, s3 = 0.f;
#pragma unroll
    for (int i = 0; i < 24; i += 4) {
        s0 = fmaf(a.v[i+0], b.v[i+0], s0);
        s1 = fmaf(a.v[i+1], b.v[i+1], s1);
        s2 = fmaf(a.v[i+2], b.v[i+2], s2);
        s3 = fmaf(a.v[i+3], b.v[i+3], s3);
    }
    s0 = fmaf(a.v[24], b.v[24], s0);
    return (s0 + s1) + (s2 + s3);
}

__global__ __launch_bounds__(256, 3) void ssm_syn_delay_kernel(
    const float* __restrict__ x,       const float* __restrict__ delay_W,
    const float* __restrict__ delay_b, const float* __restrict__ U_W,
    const float* __restrict__ U_b,     const float* __restrict__ A_W,
    const float* __restrict__ B_W,     const float* __restrict__ B_b,
    const float* __restrict__ out_W,   const float* __restrict__ out_b,
    float* __restrict__ out)
{
    // 52,800 B total -> 3 blocks/CU
    __shared__ float xs[S_ * CP];    // 22400: x[b] rows, padded
    __shared__ float dw[S_ * CP];    // 22400: delay_W rows, padded
    __shared__ float dbs[S_];        // 800
    __shared__ float lden[S_];       // 800: log(denom) per source timestep t
    __shared__ float p_s[S_ * H_];   // 6400: bgate*u, overwritten by h in phase 3

    const int tid = threadIdx.x;
    const int b   = blockIdx.x;
    const float* xb = x + (size_t)b * (S_ * C_);

    // ---- Phase 0: stage x[b] and delay_W into LDS (coalesced) ----
    for (int i = tid; i < S_ * C_; i += 256) {
        int r = i / C_, c = i - r * C_;
        xs[r * CP + c] = xb[i];
        dw[r * CP + c] = delay_W[i];
    }
    for (int i = tid; i < S_; i += 256) dbs[i] = delay_b[i];
    __syncthreads();

    // ---- Phase 1: log softmax denominators per source row t ----
    {
        const int half = tid & 1;
        const int tg   = tid >> 1;            // 0..127
        const int t0   = tg;
        const int t1   = tg + 128;
        const int t1c  = (t1 < S_) ? t1 : (S_ - 1);
        Row25 xr0 = ldrow(&xs[t0 * CP]);
        Row25 xr1 = ldrow(&xs[t1c * CP]);
        pin(xr0); pin(xr1);
        float d0 = 0.f, d1 = 0.f;
        const int sbase = half * 100;
        for (int si = 0; si < 100; ++si) {
            const int s = sbase + si;
            Row25 wr = ldrow(&dw[s * CP]);   // 2 distinct rows/wave: free broadcast
            float bias = dbs[s];
            d0 += __expf(bias + dot25(xr0, wr));
            d1 += __expf(bias + dot25(xr1, wr));
        }
        d0 += __shfl_xor(d0, 1);
        d1 += __shfl_xor(d1, 1);
        if (half == 0)       lden[t0] = __logf(d0);
        else if (t1 < S_)    lden[t1] = __logf(d1);
    }
    __syncthreads();

    // ---- Phase 2: x_del columns + u / bgate (recompute logits) ----
    {
        const int th = tid & 1;
        const int sg = tid >> 1;              // 0..127
        const int s0 = sg;
        const int s1 = sg + 128;
        const int s1c = (s1 < S_) ? s1 : (S_ - 1);
        Row25 w0 = ldrow(&dw[s0 * CP]);
        Row25 w1 = ldrow(&dw[s1c * CP]);
        pin(w0); pin(w1);                     // keep resident; no remat from LDS
        const float bias0 = dbs[s0];
        const float bias1 = dbs[s1c];
        Row25 acc0, acc1;
#pragma unroll
        for (int i = 0; i < 25; ++i) { acc0.v[i] = 0.f; acc1.v[i] = 0.f; }

        const int tbase = th * 100;
        for (int ti = 0; ti < 100; ++ti) {
            const int t = tbase + ti;
            Row25 xr = ldrow(&xs[t * CP]);   // 2 distinct rows/wave: free broadcast
            float ld = lden[t];
            float e0 = __expf(bias0 + dot25(xr, w0) - ld);
            float e1 = __expf(bias1 + dot25(xr, w1) - ld);
#pragma unroll
            for (int i = 0; i < 25; ++i) {
                acc0.v[i] = fmaf(e0, xr.v[i], acc0.v[i]);
                acc1.v[i] = fmaf(e1, xr.v[i], acc1.v[i]);
            }
        }
        // combine the two t-halves across the lane pair
#pragma unroll
        for (int i = 0; i < 25; ++i) {
            acc0.v[i] += __shfl_xor(acc0.v[i], 1);
            acc1.v[i] += __shfl_xor(acc1.v[i], 1);
        }
        const int smine = th ? s1 : s0;
        if (smine < S_) {
            Row25 a;
#pragma unroll
            for (int i = 0; i < 25; ++i) a.v[i] = th ? acc1.v[i] : acc0.v[i];
#pragma unroll
            for (int h = 0; h < H_; ++h) {
                // wave-uniform weight rows from global (L1/sL1-served)
                float uu = U_b[h];
                float bb = B_b[h];
#pragma unroll
                for (int i = 0; i < 25; ++i) {
                    uu = fmaf(a.v[i], U_W[h * C_ + i], uu);
                    bb = fmaf(a.v[i], B_W[h * C_ + i], bb);
                }
                float sg_ = 1.0f / (1.0f + __expf(-bb));
                p_s[smine * H_ + h] = uu * sg_;
            }
        }
    }
    __syncthreads();

    // ---- Phase 3: linear recurrence h_s = A h_{s-1} + p_s (8 lanes) ----
    if (tid < H_) {
        const int i = tid;
        float Ar[H_];
#pragma unroll
        for (int j = 0; j < H_; ++j) Ar[j] = A_W[i * H_ + j];
        float h = 0.f;
        for (int s = 0; s < S_; ++s) {
            float acc = p_s[s * H_ + i];
#pragma unroll
            for (int j = 0; j < H_; ++j)
                acc = fmaf(Ar[j], __shfl(h, j, 8), acc);
            h = acc;
            p_s[s * H_ + i] = h;   // overwrite in place (hs)
        }
    }
    __syncthreads();

    // ---- Phase 4: out[b,s,c] = hs[s]·out_W[c,:] + out_b[c] ----
    float* ob_ptr = out + (size_t)b * (S_ * C_);
    for (int i = tid; i < S_ * C_; i += 256) {
        int s = i / C_, c = i - s * C_;
        float v = out_b[c];
#pragma unroll
        for (int h = 0; h < H_; ++h)
            v = fmaf(p_s[s * H_ + h], out_W[c * H_ + h], v);
        ob_ptr[i] = v;
    }
}

extern "C" void kernel_launch(void* const* d_in, const int* in_sizes, int n_in,
                              void* d_out, int out_size, void* d_ws, size_t ws_size,
                              hipStream_t stream) {
    const float* x       = (const float*)d_in[0];
    const float* delay_W = (const float*)d_in[1];
    const float* delay_b = (const float*)d_in[2];
    const float* U_W     = (const float*)d_in[3];
    const float* U_b     = (const float*)d_in[4];
    const float* A_W     = (const float*)d_in[5];
    const float* B_W     = (const float*)d_in[6];
    const float* B_b     = (const float*)d_in[7];
    const float* out_W   = (const float*)d_in[8];
    const float* out_b   = (const float*)d_in[9];
    float* out = (float*)d_out;

    ssm_syn_delay_kernel<<<NB, 256, 0, stream>>>(
        x, delay_W, delay_b, U_W, U_b, A_W, B_W, B_b, out_W, out_b, out);
}